// Round 4
// baseline (3428.286 us; speedup 1.0000x reference)
//
#include <hip/hip_runtime.h>
#include <hip/hip_bf16.h>

// DeformableTransformerDecoderLayer on MI355X — Round 3.
// Adds RUNTIME INPUT-DTYPE DETECTION (f32 vs bf16) with uniform device branch.
//   E=256 NH=8 HD=32 NL=4 NP=4 DFFN=1024, nq=900 bs=8 Ls=100 Lv=21760.
// Internal pipeline buffers: bf16 (T5 running tgt: f32). Math in f32.
//
// Arena (byte offsets), S = 7200*256 = 1,843,200 elems:
//   T5 f32 [S]        @ 0           running tgt (f32 accumulator)
//   B1 bf16 [S]       @ 7,372,800   q=tgt(+pos) | deform samp
//   B2 bf16 [2S]      @ 11,059,200  self QK | cross q | val(spans B3) | FFN hidden
//   B3 bf16 [S+64K]   @ 18,432,000  self V | cross KV | val tail
//   B4 bf16 [S]       @ 22,249,472  attn out | deform off
//   B5 bf16 [S]       @ 25,935,872  proj out | deform awl
//   FLAG int          @ 29,622,272  detected input dtype (1=f32, 0=bf16)
// NEEDED = 29,622,528 bytes.

typedef __hip_bfloat16 bf16;

__device__ __forceinline__ float toF(bf16 x) { return __bfloat162float(x); }

// Load element i of an external tensor whose dtype is runtime-selected.
__device__ __forceinline__ float ldF(const void* p, size_t i, int f32mode) {
    if (f32mode) return ((const float*)p)[i];
    return __bfloat162float(((const bf16*)p)[i]);
}
__device__ __forceinline__ void stF(void* p, size_t i, int f32mode, float v) {
    if (f32mode) ((float*)p)[i] = v;
    else ((bf16*)p)[i] = __float2bfloat16(v);
}
// mode codes at call sites: 0 = bf16 (ws), 1 = f32 (ws), 2 = external (use flag)
__device__ __forceinline__ int decode(int code, int fl) { return code == 2 ? fl : code; }

// ---------------------------------------------------------------------------
// Input dtype detector: scan first 2048 ushorts of tgt as bf16 bit patterns.
// True bf16 activations (~0.1 scale) never have exponent >= 0xC0 (|x|>=2^65);
// f32 data read as ushort halves hits that with ~certainty over 1024 samples.
// ---------------------------------------------------------------------------
__global__ __launch_bounds__(256) void detect_kernel(
    const unsigned short* __restrict__ t, int* __restrict__ flag)
{
    __shared__ int bad;
    if (threadIdx.x == 0) bad = 0;
    __syncthreads();
    int my = 0;
    for (int k = 0; k < 8; k++) {
        unsigned u = t[threadIdx.x + 256 * k];
        unsigned e = (u >> 7) & 0xFF;
        if (e >= 0xC0) my = 1;
    }
    if (my) atomicOr(&bad, 1);
    __syncthreads();
    if (threadIdx.x == 0) *flag = bad;
}

__global__ __launch_bounds__(256) void dbg_kernel(bf16* out, int n, float v)
{
    int i = blockIdx.x * 256 + threadIdx.x;
    if (i < n) out[i] = __float2bfloat16(v);
}

// ---------------------------------------------------------------------------
// Tiled GEMM: C[M,N] = A[M,K] @ W[N,K]^T + bias[N] (optional ReLU).
// A: external(void*+mode) or ws; W/bias: ALWAYS external (flag dtype).
// C: always ws bf16. aOff/wOff/bOff are ELEMENT offsets (dtype-agnostic).
// ---------------------------------------------------------------------------
#define BKG 16

template <bool RELU>
__global__ __launch_bounds__(256) void gemm_kernel(
    const void* __restrict__ A, int lda, size_t aOff, int aCode,
    const void* __restrict__ W, size_t wOff,
    const void* __restrict__ bias, size_t bOff,
    bf16* __restrict__ C, int ldc,
    int M, int N, int K, const int* __restrict__ flagp)
{
    const int fl = *flagp;
    const int am = decode(aCode, fl);
    __shared__ float As[BKG][64 + 1];
    __shared__ float Ws[BKG][64 + 1];
    const int tid = threadIdx.x;
    const int bm = blockIdx.y * 64;
    const int bn = blockIdx.x * 64;
    const int tx = tid & 15;
    const int ty = tid >> 4;
    const int lk = tid & 15;
    const int lrow = tid >> 4;

    float acc[4][4] = {};

    for (int k0 = 0; k0 < K; k0 += BKG) {
#pragma unroll
        for (int i = 0; i < 4; i++) {
            int m = lrow + i * 16;
            int gm = bm + m;
            float v = 0.f;
            if (gm < M) v = ldF(A, aOff + (size_t)gm * lda + k0 + lk, am);
            As[lk][m] = v;
        }
#pragma unroll
        for (int i = 0; i < 4; i++) {
            int n = lrow + i * 16;
            int gn = bn + n;
            float v = 0.f;
            if (gn < N) v = ldF(W, wOff + (size_t)gn * K + k0 + lk, fl);
            Ws[lk][n] = v;
        }
        __syncthreads();
#pragma unroll
        for (int kk = 0; kk < BKG; kk++) {
            float a[4], b[4];
#pragma unroll
            for (int i = 0; i < 4; i++) a[i] = As[kk][ty * 4 + i];
#pragma unroll
            for (int j = 0; j < 4; j++) b[j] = Ws[kk][tx * 4 + j];
#pragma unroll
            for (int i = 0; i < 4; i++)
#pragma unroll
                for (int j = 0; j < 4; j++) acc[i][j] += a[i] * b[j];
        }
        __syncthreads();
    }

#pragma unroll
    for (int i = 0; i < 4; i++) {
        int gm = bm + ty * 4 + i;
        if (gm >= M) continue;
#pragma unroll
        for (int j = 0; j < 4; j++) {
            int gn = bn + tx * 4 + j;
            if (gn >= N) continue;
            float v = acc[i][j] + ldF(bias, bOff + gn, fl);
            if (RELU) v = fmaxf(v, 0.f);
            C[(size_t)gm * ldc + gn] = __float2bfloat16(v);
        }
    }
}

// ---------------------------------------------------------------------------
__global__ __launch_bounds__(256) void add_kernel(
    const void* __restrict__ A, int aCode, const void* __restrict__ B,
    bf16* __restrict__ out, int n, const int* __restrict__ flagp)
{
    const int fl = *flagp;
    const int am = decode(aCode, fl);
    int i = blockIdx.x * 256 + threadIdx.x;
    if (i < n) out[i] = __float2bfloat16(ldF(A, i, am) + ldF(B, i, fl));
}

// ---------------------------------------------------------------------------
// Fused residual + LayerNorm over E=256. out = LN(A + R) * w + b.
// A: ws bf16. R: ws f32 or external. w,b: external. out: ws f32 or external.
// ---------------------------------------------------------------------------
__global__ __launch_bounds__(256) void ln_res_kernel(
    const bf16* __restrict__ A, const void* __restrict__ R, int rCode,
    const void* __restrict__ w, const void* __restrict__ b,
    void* __restrict__ out, int oCode, const int* __restrict__ flagp)
{
    const int fl = *flagp;
    const int rm = decode(rCode, fl);
    const int om = decode(oCode, fl);
    const int r = blockIdx.x, tid = threadIdx.x;
    const size_t o = (size_t)r * 256 + tid;
    float x = toF(A[o]) + ldF(R, o, rm);
    __shared__ float red[256];
    red[tid] = x;
    __syncthreads();
    for (int st = 128; st > 0; st >>= 1) {
        if (tid < st) red[tid] += red[tid + st];
        __syncthreads();
    }
    float mean = red[0] * (1.f / 256.f);
    __syncthreads();
    float dx = x - mean;
    red[tid] = dx * dx;
    __syncthreads();
    for (int st = 128; st > 0; st >>= 1) {
        if (tid < st) red[tid] += red[tid + st];
        __syncthreads();
    }
    float var = red[0] * (1.f / 256.f);
    float y = dx * rsqrtf(var + 1e-5f) * ldF(w, tid, fl) + ldF(b, tid, fl);
    stF(out, o, om, y);
}

// ---------------------------------------------------------------------------
// Fused attention (scores in LDS; Lk <= 900). One block per (qi, b, h).
// All operands are ws bf16 — no dtype dispatch needed.
// ---------------------------------------------------------------------------
__global__ __launch_bounds__(256) void attn_kernel(
    const bf16* __restrict__ Q, int qs0, int qs1,
    const bf16* __restrict__ K, int ks0, int ks1,
    const bf16* __restrict__ V, int vs0, int vs1,
    bf16* __restrict__ O, int Lk, float scale)
{
    const int blk = blockIdx.x;  // qi*64 + b*8 + h
    const int h = blk & 7;
    const int b = (blk >> 3) & 7;
    const int qi = blk >> 6;
    const int tid = threadIdx.x;

    __shared__ float qv[32];
    __shared__ float sc[928];
    __shared__ float red[256];
    __shared__ float oacc[256];

    const bf16* Kb = K + (size_t)b * ks1 + h * 32;
    const bf16* Vb = V + (size_t)b * vs1 + h * 32;

    if (tid < 32) qv[tid] = toF(Q[(size_t)qi * qs0 + (size_t)b * qs1 + h * 32 + tid]);
    __syncthreads();

    float lmax = -1e30f;
    for (int ki = tid; ki < Lk; ki += 256) {
        const bf16* kp = Kb + (size_t)ki * ks0;
        float s = 0.f;
#pragma unroll
        for (int d = 0; d < 32; d++) s += qv[d] * toF(kp[d]);
        s *= scale;
        sc[ki] = s;
        lmax = fmaxf(lmax, s);
    }
    red[tid] = lmax;
    __syncthreads();
    for (int st = 128; st > 0; st >>= 1) {
        if (tid < st) red[tid] = fmaxf(red[tid], red[tid + st]);
        __syncthreads();
    }
    float gmax = red[0];
    __syncthreads();
    float lsum = 0.f;
    for (int ki = tid; ki < Lk; ki += 256) {
        float e = expf(sc[ki] - gmax);
        sc[ki] = e;
        lsum += e;
    }
    red[tid] = lsum;
    __syncthreads();
    for (int st = 128; st > 0; st >>= 1) {
        if (tid < st) red[tid] += red[tid + st];
        __syncthreads();
    }
    float gsum = red[0];

    const int d = tid & 31, g = tid >> 5;
    float po = 0.f;
    for (int ki = g; ki < Lk; ki += 8) {
        po += sc[ki] * toF(Vb[(size_t)ki * vs0 + d]);
    }
    oacc[tid] = po;
    __syncthreads();
    if (tid < 32) {
        float s = 0.f;
#pragma unroll
        for (int gg = 0; gg < 8; gg++) s += oacc[gg * 32 + tid];
        O[((size_t)qi * 8 + b) * 256 + h * 32 + tid] = __float2bfloat16(s / gsum);
    }
}

// ---------------------------------------------------------------------------
// Deformable sampling, single batch bb. One block per q; r = q*8+bb.
// val/off/awl/samp: ws bf16. refp: external (flag dtype).
// ---------------------------------------------------------------------------
__device__ __forceinline__ float sample_one(const bf16* __restrict__ val,
                                            int base, int HW, int yi, int xi,
                                            int hd32)
{
    bool valid = (xi >= 0) && (xi < HW) && (yi >= 0) && (yi < HW);
    int ix = min(max(xi, 0), HW - 1);
    int iy = min(max(yi, 0), HW - 1);
    size_t idx = (size_t)(base + iy * HW + ix) * 256 + hd32;
    float v = toF(val[idx]);
    return valid ? v : 0.f;
}

__global__ __launch_bounds__(256) void deform_kernel(
    const bf16* __restrict__ val,
    const bf16* __restrict__ off,
    const bf16* __restrict__ awl,
    const void* __restrict__ refp,
    bf16* __restrict__ samp, int bb, const int* __restrict__ flagp)
{
    const int fl = *flagp;
    const int levH[4] = {128, 64, 32, 16};
    const int levS[4] = {0, 16384, 20480, 21504};
    const int r = blockIdx.x * 8 + bb;
    const int tid = threadIdx.x;
    const int h = tid >> 5, d = tid & 31;
    const int hd32 = h * 32 + d;

    const bf16* lg = awl + (size_t)r * 128 + h * 16;
    float w[16];
    float mx = -1e30f;
#pragma unroll
    for (int i = 0; i < 16; i++) { w[i] = toF(lg[i]); mx = fmaxf(mx, w[i]); }
    float sm = 0.f;
#pragma unroll
    for (int i = 0; i < 16; i++) { w[i] = expf(w[i] - mx); sm += w[i]; }
    float inv = 1.f / sm;

    const bf16* offr = off + (size_t)r * 256 + h * 32;
    float acc = 0.f;
#pragma unroll
    for (int l = 0; l < 4; l++) {
        const int HW = levH[l];
        const int base = levS[l];
        float rx = ldF(refp, (size_t)r * 16 + l * 4 + 0, fl);
        float ry = ldF(refp, (size_t)r * 16 + l * 4 + 1, fl);
        float rw = ldF(refp, (size_t)r * 16 + l * 4 + 2, fl);
        float rh = ldF(refp, (size_t)r * 16 + l * 4 + 3, fl);
#pragma unroll
        for (int p = 0; p < 4; p++) {
            float ox = toF(offr[l * 8 + p * 2 + 0]);
            float oy = toF(offr[l * 8 + p * 2 + 1]);
            float locx = rx + ox * 0.125f * rw;   // off/NP * wh * 0.5
            float locy = ry + oy * 0.125f * rh;
            float x = locx * HW - 0.5f;
            float y = locy * HW - 0.5f;
            float x0f = floorf(x), y0f = floorf(y);
            int x0 = (int)x0f, y0 = (int)y0f;
            float fx = x - x0f, fy = y - y0f;
            float wgt = w[l * 4 + p] * inv;
            float s00 = sample_one(val, base, HW, y0,     x0,     hd32);
            float s01 = sample_one(val, base, HW, y0,     x0 + 1, hd32);
            float s10 = sample_one(val, base, HW, y0 + 1, x0,     hd32);
            float s11 = sample_one(val, base, HW, y0 + 1, x0 + 1, hd32);
            acc += wgt * (s00 * (1.f - fx) * (1.f - fy) + s01 * fx * (1.f - fy) +
                          s10 * (1.f - fx) * fy + s11 * fx * fy);
        }
    }
    samp[(size_t)r * 256 + tid] = __float2bfloat16(acc);
}

// ---------------------------------------------------------------------------
extern "C" void kernel_launch(void* const* d_in, const int* in_sizes, int n_in,
                              void* d_out, int out_size, void* d_ws, size_t ws_size,
                              hipStream_t stream)
{
    (void)in_sizes; (void)n_in;
    const void* tgt      = d_in[0];
    const void* tgt_pos  = d_in[1];
    const void* refp     = d_in[2];
    const void* mem_sup  = d_in[3];
    const void* memory   = d_in[4];
    const void* sa_in_w  = d_in[6];
    const void* sa_in_b  = d_in[7];
    const void* sa_out_w = d_in[8];
    const void* sa_out_b = d_in[9];
    const void* cs_in_w  = d_in[10];
    const void* cs_in_b  = d_in[11];
    const void* cs_out_w = d_in[12];
    const void* cs_out_b = d_in[13];
    const void* so_w = d_in[14];
    const void* so_b = d_in[15];
    const void* aw_w = d_in[16];
    const void* aw_b = d_in[17];
    const void* vp_w = d_in[18];
    const void* vp_b = d_in[19];
    const void* op_w = d_in[20];
    const void* op_b = d_in[21];
    const void* n1w = d_in[22];
    const void* n1b = d_in[23];
    const void* n2w = d_in[24];
    const void* n2b = d_in[25];
    const void* csnw = d_in[26];
    const void* csnb = d_in[27];
    const void* n3w = d_in[28];
    const void* n3b = d_in[29];
    const void* l1w = d_in[30];
    const void* l1b = d_in[31];
    const void* l2w = d_in[32];
    const void* l2b = d_in[33];

    const int S = 900 * 8 * 256;
    const size_t NEEDED = 29622528;
    const dim3 blk(256);

    if (ws_size < NEEDED) {
        dbg_kernel<<<(out_size + 255) / 256, blk, 0, stream>>>(
            (bf16*)d_out, out_size, (float)(ws_size >> 20));
        return;
    }

    char* base = (char*)d_ws;
    float* T5 = (float*)base;              // [S] f32
    bf16* B1  = (bf16*)(base + 7372800);   // [S]
    bf16* B2  = (bf16*)(base + 11059200);  // [2S]
    bf16* B3  = (bf16*)(base + 18432000);  // [S + 64K elems]
    bf16* B4  = (bf16*)(base + 22249472);  // [S]
    bf16* B5  = (bf16*)(base + 25935872);  // [S]
    int* FL   = (int*)(base + 29622272);

    const float scale = 0.1767766953f;  // 1/sqrt(32)
    const int MT = 7200;
    const int gm = 113;  // ceil(7200/64)

    detect_kernel<<<1, blk, 0, stream>>>((const unsigned short*)tgt, FL);

    // ---- self attention ----
    add_kernel<<<MT, blk, 0, stream>>>(tgt, 2, tgt_pos, B1, S, FL);
    gemm_kernel<false><<<dim3(8, gm), blk, 0, stream>>>(
        B1, 256, 0, 0, sa_in_w, 0, sa_in_b, 0, B2, 512, MT, 512, 256, FL);  // q,k
    gemm_kernel<false><<<dim3(4, gm), blk, 0, stream>>>(
        tgt, 256, 0, 2, sa_in_w, 131072, sa_in_b, 512, B3, 256, MT, 256, 256, FL);  // v
    attn_kernel<<<900 * 64, blk, 0, stream>>>(
        B2, 4096, 512, B2 + 256, 4096, 512, B3, 2048, 256, B4, 900, scale);
    gemm_kernel<false><<<dim3(4, gm), blk, 0, stream>>>(
        B4, 256, 0, 0, sa_out_w, 0, sa_out_b, 0, B5, 256, MT, 256, 256, FL);
    ln_res_kernel<<<MT, blk, 0, stream>>>(B5, tgt, 2, n2w, n2b, T5, 1, FL);

    // ---- cross attention (memory_support, Lk=100) ----
    add_kernel<<<MT, blk, 0, stream>>>(T5, 1, tgt_pos, B1, S, FL);
    gemm_kernel<false><<<dim3(4, gm), blk, 0, stream>>>(
        B1, 256, 0, 0, cs_in_w, 0, cs_in_b, 0, B2, 256, MT, 256, 256, FL);  // q
    gemm_kernel<false><<<dim3(8, 13), blk, 0, stream>>>(
        mem_sup, 256, 0, 2, cs_in_w, 65536, cs_in_b, 256, B3, 512, 800, 512, 256, FL);  // k,v
    attn_kernel<<<900 * 64, blk, 0, stream>>>(
        B2, 2048, 256, B3, 512, 51200, B3 + 256, 512, 51200, B4, 100, scale);
    gemm_kernel<false><<<dim3(4, gm), blk, 0, stream>>>(
        B4, 256, 0, 0, cs_out_w, 0, cs_out_b, 0, B5, 256, MT, 256, 256, FL);
    ln_res_kernel<<<MT, blk, 0, stream>>>(B5, T5, 1, csnw, csnb, T5, 1, FL);

    // ---- deformable attention ----
    add_kernel<<<MT, blk, 0, stream>>>(T5, 1, tgt_pos, B1, S, FL);  // query
    gemm_kernel<false><<<dim3(4, gm), blk, 0, stream>>>(
        B1, 256, 0, 0, so_w, 0, so_b, 0, B4, 256, MT, 256, 256, FL);        // offsets
    gemm_kernel<false><<<dim3(2, gm), blk, 0, stream>>>(
        B1, 256, 0, 0, aw_w, 0, aw_b, 0, B5, 128, MT, 128, 256, FL);        // aw logits
    for (int b = 0; b < 8; b++) {
        gemm_kernel<false><<<dim3(4, 340), blk, 0, stream>>>(
            memory, 2048, (size_t)b * 256, 2, vp_w, 0, vp_b, 0, B2, 256,
            21760, 256, 256, FL);                                           // val proj
        deform_kernel<<<900, blk, 0, stream>>>(B2, B4, B5, refp, B1, b, FL);
    }
    gemm_kernel<false><<<dim3(4, gm), blk, 0, stream>>>(
        B1, 256, 0, 0, op_w, 0, op_b, 0, B5, 256, MT, 256, 256, FL);        // out proj
    ln_res_kernel<<<MT, blk, 0, stream>>>(B5, T5, 1, n1w, n1b, T5, 1, FL);

    // ---- FFN (4 chunks of 1800 rows; hidden chunk in B2) ----
    for (int c = 0; c < 4; c++) {
        int m0 = c * 1800;
        gemm_kernel<true><<<dim3(16, 29), blk, 0, stream>>>(
            T5, 256, (size_t)m0 * 256, 1, l1w, 0, l1b, 0, B2, 1024,
            1800, 1024, 256, FL);
        gemm_kernel<false><<<dim3(4, 29), blk, 0, stream>>>(
            B2, 1024, 0, 0, l2w, 0, l2b, 0, B5 + (size_t)m0 * 256, 256,
            1800, 256, 1024, FL);
    }
    ln_res_kernel<<<MT, blk, 0, stream>>>(B5, T5, 1, n3w, n3b, d_out, 2, FL);
}

// Round 5
// 2599.625 us; speedup vs baseline: 1.3188x; 1.3188x over previous
//
#include <hip/hip_runtime.h>
#include <hip/hip_bf16.h>

// DeformableTransformerDecoderLayer on MI355X — Round 4.
// R3 passed (3428 us). This round: MFMA bf16 GEMM (wave-per-16x64 strip)
// replaces the scalar GEMM. Attention/deform/LN unchanged.
//   E=256 NH=8 HD=32 NL=4 NP=4 DFFN=1024, nq=900 bs=8 Ls=100 Lv=21760.
// Externals are f32 (runtime-detected); internal ws buffers bf16 (T5 f32).
//
// Arena (byte offsets), S = 7200*256 = 1,843,200 elems:
//   T5 f32 [S]        @ 0           running tgt (f32 accumulator)
//   B1 bf16 [S]       @ 7,372,800   q=tgt(+pos) | deform samp
//   B2 bf16 [2S]      @ 11,059,200  self QK | cross q | val(spans B3) | FFN hidden
//   B3 bf16 [S+64K]   @ 18,432,000  self V | cross KV | val tail
//   B4 bf16 [S]       @ 22,249,472  attn out | deform off
//   B5 bf16 [S]       @ 25,935,872  proj out | deform awl
//   FLAG int          @ 29,622,272  detected input dtype (1=f32, 0=bf16)
// NEEDED = 29,622,528 bytes.

typedef __hip_bfloat16 bf16;
typedef __attribute__((ext_vector_type(8))) short short8;
typedef __attribute__((ext_vector_type(4))) float f32x4;

__device__ __forceinline__ float toF(bf16 x) { return __bfloat162float(x); }

__device__ __forceinline__ float ldF(const void* p, size_t i, int f32mode) {
    if (f32mode) return ((const float*)p)[i];
    return __bfloat162float(((const bf16*)p)[i]);
}
__device__ __forceinline__ void stF(void* p, size_t i, int f32mode, float v) {
    if (f32mode) ((float*)p)[i] = v;
    else ((bf16*)p)[i] = __float2bfloat16(v);
}
// mode codes: 0 = bf16 (ws), 1 = f32 (ws), 2 = external (use flag)
__device__ __forceinline__ int decode(int code, int fl) { return code == 2 ? fl : code; }

__device__ __forceinline__ short f2b(float x) {
    bf16 h = __float2bfloat16(x);
    return *(short*)&h;
}

// Load 8 consecutive elements starting at element idx as a bf16x8 fragment.
// idx is 8-element aligned. f32 path: 2x float4 + 8 converts.
__device__ __forceinline__ short8 loadFrag8(const void* p, size_t idx, int f32m) {
    short8 r;
    if (f32m) {
        const float4* q = (const float4*)((const float*)p + idx);
        float4 u = q[0];
        float4 v = q[1];
        r[0] = f2b(u.x); r[1] = f2b(u.y); r[2] = f2b(u.z); r[3] = f2b(u.w);
        r[4] = f2b(v.x); r[5] = f2b(v.y); r[6] = f2b(v.z); r[7] = f2b(v.w);
    } else {
        r = *(const short8*)((const bf16*)p + idx);
    }
    return r;
}

// ---------------------------------------------------------------------------
// Input dtype detector (unchanged from R3).
// ---------------------------------------------------------------------------
__global__ __launch_bounds__(256) void detect_kernel(
    const unsigned short* __restrict__ t, int* __restrict__ flag)
{
    __shared__ int bad;
    if (threadIdx.x == 0) bad = 0;
    __syncthreads();
    int my = 0;
    for (int k = 0; k < 8; k++) {
        unsigned u = t[threadIdx.x + 256 * k];
        unsigned e = (u >> 7) & 0xFF;
        if (e >= 0xC0) my = 1;
    }
    if (my) atomicOr(&bad, 1);
    __syncthreads();
    if (threadIdx.x == 0) *flag = bad;
}

__global__ __launch_bounds__(256) void dbg_kernel(bf16* out, int n, float v)
{
    int i = blockIdx.x * 256 + threadIdx.x;
    if (i < n) out[i] = __float2bfloat16(v);
}

// ---------------------------------------------------------------------------
// MFMA GEMM: C[M,N](bf16 ws) = A[M,K] @ W[N,K]^T + bias[N], optional ReLU.
// Block = 256 thr = 4 waves; block tile 64(M)x64(N); wave -> 16(M)x64(N).
// mfma_f32_16x16x32_bf16; A-frag A[m=lane&15][k=quad*8+j], B-frag
// W[n=lane&15][k=quad*8+j]; C/D col=lane&15, row=quad*4+reg.
// K % 32 == 0, N % 64 == 0 (grid.x = N/64); M arbitrary (clamp+predicate).
// ---------------------------------------------------------------------------
template <bool RELU>
__global__ __launch_bounds__(256) void mgemm_kernel(
    const void* __restrict__ A, int lda, size_t aOff, int aCode,
    const void* __restrict__ W, size_t wOff,
    const void* __restrict__ bias, size_t bOff,
    bf16* __restrict__ C, int ldc,
    int M, int N, int K, const int* __restrict__ flagp)
{
    const int fl = *flagp;
    const int am = decode(aCode, fl);
    const int tid = threadIdx.x;
    const int lane = tid & 63;
    const int wv = tid >> 6;
    const int l15 = lane & 15;
    const int quad = lane >> 4;
    const int bm = blockIdx.y * 64 + wv * 16;
    const int bn = blockIdx.x * 64;

    const int ar = min(bm + l15, M - 1);  // clamped A row (stores predicated)
    const size_t aBase = aOff + (size_t)ar * lda + quad * 8;

    f32x4 acc[4] = {};

    for (int k0 = 0; k0 < K; k0 += 32) {
        short8 af = loadFrag8(A, aBase + k0, am);
#pragma unroll
        for (int nt = 0; nt < 4; nt++) {
            int n = bn + nt * 16 + l15;
            short8 bfr = loadFrag8(W, wOff + (size_t)n * K + quad * 8 + k0, fl);
            acc[nt] = __builtin_amdgcn_mfma_f32_16x16x32_bf16(af, bfr, acc[nt], 0, 0, 0);
        }
    }

#pragma unroll
    for (int nt = 0; nt < 4; nt++) {
        int n = bn + nt * 16 + l15;
        float bv = ldF(bias, bOff + n, fl);
#pragma unroll
        for (int r = 0; r < 4; r++) {
            int row = bm + quad * 4 + r;
            if (row < M) {
                float v = acc[nt][r] + bv;
                if (RELU) v = fmaxf(v, 0.f);
                C[(size_t)row * ldc + n] = __float2bfloat16(v);
            }
        }
    }
}

// ---------------------------------------------------------------------------
__global__ __launch_bounds__(256) void add_kernel(
    const void* __restrict__ A, int aCode, const void* __restrict__ B,
    bf16* __restrict__ out, int n, const int* __restrict__ flagp)
{
    const int fl = *flagp;
    const int am = decode(aCode, fl);
    int i = blockIdx.x * 256 + threadIdx.x;
    if (i < n) out[i] = __float2bfloat16(ldF(A, i, am) + ldF(B, i, fl));
}

// ---------------------------------------------------------------------------
// Fused residual + LayerNorm over E=256 (unchanged).
// ---------------------------------------------------------------------------
__global__ __launch_bounds__(256) void ln_res_kernel(
    const bf16* __restrict__ A, const void* __restrict__ R, int rCode,
    const void* __restrict__ w, const void* __restrict__ b,
    void* __restrict__ out, int oCode, const int* __restrict__ flagp)
{
    const int fl = *flagp;
    const int rm = decode(rCode, fl);
    const int om = decode(oCode, fl);
    const int r = blockIdx.x, tid = threadIdx.x;
    const size_t o = (size_t)r * 256 + tid;
    float x = toF(A[o]) + ldF(R, o, rm);
    __shared__ float red[256];
    red[tid] = x;
    __syncthreads();
    for (int st = 128; st > 0; st >>= 1) {
        if (tid < st) red[tid] += red[tid + st];
        __syncthreads();
    }
    float mean = red[0] * (1.f / 256.f);
    __syncthreads();
    float dx = x - mean;
    red[tid] = dx * dx;
    __syncthreads();
    for (int st = 128; st > 0; st >>= 1) {
        if (tid < st) red[tid] += red[tid + st];
        __syncthreads();
    }
    float var = red[0] * (1.f / 256.f);
    float y = dx * rsqrtf(var + 1e-5f) * ldF(w, tid, fl) + ldF(b, tid, fl);
    stF(out, o, om, y);
}

// ---------------------------------------------------------------------------
// Fused attention (unchanged this round; next optimization target).
// ---------------------------------------------------------------------------
__global__ __launch_bounds__(256) void attn_kernel(
    const bf16* __restrict__ Q, int qs0, int qs1,
    const bf16* __restrict__ K, int ks0, int ks1,
    const bf16* __restrict__ V, int vs0, int vs1,
    bf16* __restrict__ O, int Lk, float scale)
{
    const int blk = blockIdx.x;  // qi*64 + b*8 + h
    const int h = blk & 7;
    const int b = (blk >> 3) & 7;
    const int qi = blk >> 6;
    const int tid = threadIdx.x;

    __shared__ float qv[32];
    __shared__ float sc[928];
    __shared__ float red[256];
    __shared__ float oacc[256];

    const bf16* Kb = K + (size_t)b * ks1 + h * 32;
    const bf16* Vb = V + (size_t)b * vs1 + h * 32;

    if (tid < 32) qv[tid] = toF(Q[(size_t)qi * qs0 + (size_t)b * qs1 + h * 32 + tid]);
    __syncthreads();

    float lmax = -1e30f;
    for (int ki = tid; ki < Lk; ki += 256) {
        const bf16* kp = Kb + (size_t)ki * ks0;
        float s = 0.f;
#pragma unroll
        for (int d = 0; d < 32; d++) s += qv[d] * toF(kp[d]);
        s *= scale;
        sc[ki] = s;
        lmax = fmaxf(lmax, s);
    }
    red[tid] = lmax;
    __syncthreads();
    for (int st = 128; st > 0; st >>= 1) {
        if (tid < st) red[tid] = fmaxf(red[tid], red[tid + st]);
        __syncthreads();
    }
    float gmax = red[0];
    __syncthreads();
    float lsum = 0.f;
    for (int ki = tid; ki < Lk; ki += 256) {
        float e = expf(sc[ki] - gmax);
        sc[ki] = e;
        lsum += e;
    }
    red[tid] = lsum;
    __syncthreads();
    for (int st = 128; st > 0; st >>= 1) {
        if (tid < st) red[tid] += red[tid + st];
        __syncthreads();
    }
    float gsum = red[0];

    const int d = tid & 31, g = tid >> 5;
    float po = 0.f;
    for (int ki = g; ki < Lk; ki += 8) {
        po += sc[ki] * toF(Vb[(size_t)ki * vs0 + d]);
    }
    oacc[tid] = po;
    __syncthreads();
    if (tid < 32) {
        float s = 0.f;
#pragma unroll
        for (int gg = 0; gg < 8; gg++) s += oacc[gg * 32 + tid];
        O[((size_t)qi * 8 + b) * 256 + h * 32 + tid] = __float2bfloat16(s / gsum);
    }
}

// ---------------------------------------------------------------------------
// Deformable sampling, single batch bb (unchanged).
// ---------------------------------------------------------------------------
__device__ __forceinline__ float sample_one(const bf16* __restrict__ val,
                                            int base, int HW, int yi, int xi,
                                            int hd32)
{
    bool valid = (xi >= 0) && (xi < HW) && (yi >= 0) && (yi < HW);
    int ix = min(max(xi, 0), HW - 1);
    int iy = min(max(yi, 0), HW - 1);
    size_t idx = (size_t)(base + iy * HW + ix) * 256 + hd32;
    float v = toF(val[idx]);
    return valid ? v : 0.f;
}

__global__ __launch_bounds__(256) void deform_kernel(
    const bf16* __restrict__ val,
    const bf16* __restrict__ off,
    const bf16* __restrict__ awl,
    const void* __restrict__ refp,
    bf16* __restrict__ samp, int bb, const int* __restrict__ flagp)
{
    const int fl = *flagp;
    const int levH[4] = {128, 64, 32, 16};
    const int levS[4] = {0, 16384, 20480, 21504};
    const int r = blockIdx.x * 8 + bb;
    const int tid = threadIdx.x;
    const int h = tid >> 5, d = tid & 31;
    const int hd32 = h * 32 + d;

    const bf16* lg = awl + (size_t)r * 128 + h * 16;
    float w[16];
    float mx = -1e30f;
#pragma unroll
    for (int i = 0; i < 16; i++) { w[i] = toF(lg[i]); mx = fmaxf(mx, w[i]); }
    float sm = 0.f;
#pragma unroll
    for (int i = 0; i < 16; i++) { w[i] = expf(w[i] - mx); sm += w[i]; }
    float inv = 1.f / sm;

    const bf16* offr = off + (size_t)r * 256 + h * 32;
    float acc = 0.f;
#pragma unroll
    for (int l = 0; l < 4; l++) {
        const int HW = levH[l];
        const int base = levS[l];
        float rx = ldF(refp, (size_t)r * 16 + l * 4 + 0, fl);
        float ry = ldF(refp, (size_t)r * 16 + l * 4 + 1, fl);
        float rw = ldF(refp, (size_t)r * 16 + l * 4 + 2, fl);
        float rh = ldF(refp, (size_t)r * 16 + l * 4 + 3, fl);
#pragma unroll
        for (int p = 0; p < 4; p++) {
            float ox = toF(offr[l * 8 + p * 2 + 0]);
            float oy = toF(offr[l * 8 + p * 2 + 1]);
            float locx = rx + ox * 0.125f * rw;   // off/NP * wh * 0.5
            float locy = ry + oy * 0.125f * rh;
            float x = locx * HW - 0.5f;
            float y = locy * HW - 0.5f;
            float x0f = floorf(x), y0f = floorf(y);
            int x0 = (int)x0f, y0 = (int)y0f;
            float fx = x - x0f, fy = y - y0f;
            float wgt = w[l * 4 + p] * inv;
            float s00 = sample_one(val, base, HW, y0,     x0,     hd32);
            float s01 = sample_one(val, base, HW, y0,     x0 + 1, hd32);
            float s10 = sample_one(val, base, HW, y0 + 1, x0,     hd32);
            float s11 = sample_one(val, base, HW, y0 + 1, x0 + 1, hd32);
            acc += wgt * (s00 * (1.f - fx) * (1.f - fy) + s01 * fx * (1.f - fy) +
                          s10 * (1.f - fx) * fy + s11 * fx * fy);
        }
    }
    samp[(size_t)r * 256 + tid] = __float2bfloat16(acc);
}

// ---------------------------------------------------------------------------
extern "C" void kernel_launch(void* const* d_in, const int* in_sizes, int n_in,
                              void* d_out, int out_size, void* d_ws, size_t ws_size,
                              hipStream_t stream)
{
    (void)in_sizes; (void)n_in;
    const void* tgt      = d_in[0];
    const void* tgt_pos  = d_in[1];
    const void* refp     = d_in[2];
    const void* mem_sup  = d_in[3];
    const void* memory   = d_in[4];
    const void* sa_in_w  = d_in[6];
    const void* sa_in_b  = d_in[7];
    const void* sa_out_w = d_in[8];
    const void* sa_out_b = d_in[9];
    const void* cs_in_w  = d_in[10];
    const void* cs_in_b  = d_in[11];
    const void* cs_out_w = d_in[12];
    const void* cs_out_b = d_in[13];
    const void* so_w = d_in[14];
    const void* so_b = d_in[15];
    const void* aw_w = d_in[16];
    const void* aw_b = d_in[17];
    const void* vp_w = d_in[18];
    const void* vp_b = d_in[19];
    const void* op_w = d_in[20];
    const void* op_b = d_in[21];
    const void* n1w = d_in[22];
    const void* n1b = d_in[23];
    const void* n2w = d_in[24];
    const void* n2b = d_in[25];
    const void* csnw = d_in[26];
    const void* csnb = d_in[27];
    const void* n3w = d_in[28];
    const void* n3b = d_in[29];
    const void* l1w = d_in[30];
    const void* l1b = d_in[31];
    const void* l2w = d_in[32];
    const void* l2b = d_in[33];

    const int S = 900 * 8 * 256;
    const size_t NEEDED = 29622528;
    const dim3 blk(256);

    if (ws_size < NEEDED) {
        dbg_kernel<<<(out_size + 255) / 256, blk, 0, stream>>>(
            (bf16*)d_out, out_size, (float)(ws_size >> 20));
        return;
    }

    char* base = (char*)d_ws;
    float* T5 = (float*)base;              // [S] f32
    bf16* B1  = (bf16*)(base + 7372800);   // [S]
    bf16* B2  = (bf16*)(base + 11059200);  // [2S]
    bf16* B3  = (bf16*)(base + 18432000);  // [S + 64K elems]
    bf16* B4  = (bf16*)(base + 22249472);  // [S]
    bf16* B5  = (bf16*)(base + 25935872);  // [S]
    int* FL   = (int*)(base + 29622272);

    const float scale = 0.1767766953f;  // 1/sqrt(32)
    const int MT = 7200;
    const int gy = 113;  // ceil(7200/64)

    detect_kernel<<<1, blk, 0, stream>>>((const unsigned short*)tgt, FL);

    // ---- self attention ----
    add_kernel<<<MT, blk, 0, stream>>>(tgt, 2, tgt_pos, B1, S, FL);
    mgemm_kernel<false><<<dim3(8, gy), blk, 0, stream>>>(
        B1, 256, 0, 0, sa_in_w, 0, sa_in_b, 0, B2, 512, MT, 512, 256, FL);  // q,k
    mgemm_kernel<false><<<dim3(4, gy), blk, 0, stream>>>(
        tgt, 256, 0, 2, sa_in_w, 131072, sa_in_b, 512, B3, 256, MT, 256, 256, FL);  // v
    attn_kernel<<<900 * 64, blk, 0, stream>>>(
        B2, 4096, 512, B2 + 256, 4096, 512, B3, 2048, 256, B4, 900, scale);
    mgemm_kernel<false><<<dim3(4, gy), blk, 0, stream>>>(
        B4, 256, 0, 0, sa_out_w, 0, sa_out_b, 0, B5, 256, MT, 256, 256, FL);
    ln_res_kernel<<<MT, blk, 0, stream>>>(B5, tgt, 2, n2w, n2b, T5, 1, FL);

    // ---- cross attention (memory_support, Lk=100) ----
    add_kernel<<<MT, blk, 0, stream>>>(T5, 1, tgt_pos, B1, S, FL);
    mgemm_kernel<false><<<dim3(4, gy), blk, 0, stream>>>(
        B1, 256, 0, 0, cs_in_w, 0, cs_in_b, 0, B2, 256, MT, 256, 256, FL);  // q
    mgemm_kernel<false><<<dim3(8, 13), blk, 0, stream>>>(
        mem_sup, 256, 0, 2, cs_in_w, 65536, cs_in_b, 256, B3, 512, 800, 512, 256, FL);  // k,v
    attn_kernel<<<900 * 64, blk, 0, stream>>>(
        B2, 2048, 256, B3, 512, 51200, B3 + 256, 512, 51200, B4, 100, scale);
    mgemm_kernel<false><<<dim3(4, gy), blk, 0, stream>>>(
        B4, 256, 0, 0, cs_out_w, 0, cs_out_b, 0, B5, 256, MT, 256, 256, FL);
    ln_res_kernel<<<MT, blk, 0, stream>>>(B5, T5, 1, csnw, csnb, T5, 1, FL);

    // ---- deformable attention ----
    add_kernel<<<MT, blk, 0, stream>>>(T5, 1, tgt_pos, B1, S, FL);  // query
    mgemm_kernel<false><<<dim3(4, gy), blk, 0, stream>>>(
        B1, 256, 0, 0, so_w, 0, so_b, 0, B4, 256, MT, 256, 256, FL);        // offsets
    mgemm_kernel<false><<<dim3(2, gy), blk, 0, stream>>>(
        B1, 256, 0, 0, aw_w, 0, aw_b, 0, B5, 128, MT, 128, 256, FL);        // aw logits
    for (int b = 0; b < 8; b++) {
        mgemm_kernel<false><<<dim3(4, 340), blk, 0, stream>>>(
            memory, 2048, (size_t)b * 256, 2, vp_w, 0, vp_b, 0, B2, 256,
            21760, 256, 256, FL);                                           // val proj
        deform_kernel<<<900, blk, 0, stream>>>(B2, B4, B5, refp, B1, b, FL);
    }
    mgemm_kernel<false><<<dim3(4, gy), blk, 0, stream>>>(
        B1, 256, 0, 0, op_w, 0, op_b, 0, B5, 256, MT, 256, 256, FL);        // out proj
    ln_res_kernel<<<MT, blk, 0, stream>>>(B5, T5, 1, n1w, n1b, T5, 1, FL);

    // ---- FFN (5 chunks of 1440 rows; hidden chunk in B2) ----
    for (int c = 0; c < 5; c++) {
        int m0 = c * 1440;
        mgemm_kernel<true><<<dim3(16, 23), blk, 0, stream>>>(
            T5, 256, (size_t)m0 * 256, 1, l1w, 0, l1b, 0, B2, 1024,
            1440, 1024, 256, FL);
        mgemm_kernel<false><<<dim3(4, 23), blk, 0, stream>>>(
            B2, 1024, 0, 0, l2w, 0, l2b, 0, B5 + (size_t)m0 * 256, 256,
            1440, 256, 1024, FL);
    }
    ln_res_kernel<<<MT, blk, 0, stream>>>(B5, T5, 1, n3w, n3b, d_out, 2, FL);
}